// Round 5
// baseline (205.854 us; speedup 1.0000x reference)
//
#include <hip/hip_runtime.h>
#include <math.h>

typedef _Float16 half8 __attribute__((ext_vector_type(8)));
typedef _Float16 half2h __attribute__((ext_vector_type(2)));
typedef float floatx4 __attribute__((ext_vector_type(4)));

#define HDIM 256
#define NC 15        // value + 4 grad + 10 hess (00,01,02,03,11,12,13,22,23,33)
#define SPB 16       // samples per block
#define KH 128       // K streamed in two halves
#define STRIDE 136   // f16 per LDS row: 128 + 8 pad
#define MROWS 240    // 15 comps * 16 samples

// ---------------------------------------------------------------------------
// Per-sample analytic Einstein tensor from (f, grad f, hess f). One lane.
// ---------------------------------------------------------------------------
__device__ __forceinline__ void einstein_tail(
    float f, const float* Gf, const float* Hs, float r, float th,
    float* __restrict__ outp)
{
    float Hf[4][4];
    {
        int qq = 0;
#pragma unroll
        for (int k = 0; k < 4; ++k)
#pragma unroll
            for (int l = k; l < 4; ++l) { Hf[k][l] = Hs[qq]; Hf[l][k] = Hs[qq]; ++qq; }
    }
    float sn = sinf(th), cs = cosf(th);
    float E  = expf(f);

    float gd[4] = {-1.f, E, r * r, r * r * sn * sn};
    float gi[4];
#pragma unroll
    for (int a = 0; a < 4; ++a) gi[a] = 1.f / gd[a];

    float dgv[4][4];
    float ddg[4][4][4];
#pragma unroll
    for (int a = 0; a < 4; ++a)
#pragma unroll
        for (int k = 0; k < 4; ++k) {
            dgv[a][k] = 0.f;
#pragma unroll
            for (int l = 0; l < 4; ++l) ddg[a][k][l] = 0.f;
        }
#pragma unroll
    for (int k = 0; k < 4; ++k) dgv[1][k] = E * Gf[k];
    dgv[2][1] = 2.f * r;
    dgv[3][1] = 2.f * r * sn * sn;
    dgv[3][2] = 2.f * r * r * sn * cs;
#pragma unroll
    for (int k = 0; k < 4; ++k)
#pragma unroll
        for (int l = 0; l < 4; ++l)
            ddg[1][k][l] = E * fmaf(Gf[k], Gf[l], Hf[k][l]);
    ddg[2][1][1] = 2.f;
    ddg[3][1][1] = 2.f * sn * sn;
    ddg[3][1][2] = 4.f * r * sn * cs;
    ddg[3][2][1] = 4.f * r * sn * cs;
    ddg[3][2][2] = 2.f * r * r * (cs * cs - sn * sn);

    auto SYMF = [&](int a, int i, int jx) -> float {
        float sy = 0.f;
        if (a == i)  sy += dgv[a][jx];
        if (a == jx) sy += dgv[a][i];
        if (i == jx) sy -= dgv[i][a];
        return sy;
    };
    auto DF = [&](int a, int i, int jx, int k) -> float {
        float ds = 0.f;
        if (a == i)  ds += ddg[a][jx][k];
        if (a == jx) ds += ddg[a][i][k];
        if (i == jx) ds -= ddg[i][a][k];
        return 0.5f * (gi[a] * ds - gi[a] * gi[a] * dgv[a][k] * SYMF(a, i, jx));
    };

    float Gm[4][4][4];
#pragma unroll
    for (int a = 0; a < 4; ++a)
#pragma unroll
        for (int i = 0; i < 4; ++i)
#pragma unroll
            for (int jx = 0; jx < 4; ++jx)
                Gm[a][i][jx] = 0.5f * gi[a] * SYMF(a, i, jx);

    float ric[4][4];
#pragma unroll
    for (int b = 0; b < 4; ++b)
#pragma unroll
        for (int d = 0; d < 4; ++d) {
            float sum = 0.f;
#pragma unroll
            for (int a = 0; a < 4; ++a) {
                sum += DF(a, d, b, a) - DF(a, a, b, d);
#pragma unroll
                for (int e = 0; e < 4; ++e)
                    sum += Gm[a][a][e] * Gm[e][d][b] - Gm[a][d][e] * Gm[e][a][b];
            }
            ric[b][d] = sum;
        }

    float Rs = 0.f;
#pragma unroll
    for (int b = 0; b < 4; ++b) Rs += gi[b] * ric[b][b];

#pragma unroll
    for (int a = 0; a < 4; ++a)
#pragma unroll
        for (int b = 0; b < 4; ++b) {
            float v = gi[a] * gi[b] * ric[a][b];
            if (a == b) v -= 0.5f * gi[a] * Rs;
            outp[a * 4 + b] = v;
        }
}

// ---------------------------------------------------------------------------
// Coalesced 64x64 LDS-tile transpose: Wt[m][j*256+k] = (f16)W_m[k*256+j].
// grid = 32 blocks (2 matrices x 16 tiles), block = 256.
// ---------------------------------------------------------------------------
__global__ __launch_bounds__(256) void pack_wt(
    const float* __restrict__ W2, const float* __restrict__ W3,
    _Float16* __restrict__ Wt)
{
    __shared__ float t[64][65];
    const int m    = blockIdx.x >> 4;
    const float* W = m ? W3 : W2;
    const int tile = blockIdx.x & 15;
    const int k0 = (tile >> 2) * 64, j0 = (tile & 3) * 64;
    const int tx = threadIdx.x & 63, ty = threadIdx.x >> 6;   // 64 x 4
#pragma unroll
    for (int i = 0; i < 16; ++i) {
        int k = ty + i * 4;
        t[k][tx] = W[(k0 + k) * HDIM + j0 + tx];              // coalesced read
    }
    __syncthreads();
#pragma unroll
    for (int i = 0; i < 16; ++i) {
        int jj = ty + i * 4;
        Wt[(size_t)m * HDIM * HDIM + (j0 + jj) * HDIM + k0 + tx] =
            (_Float16)t[tx][jj];                              // coalesced write
    }
}

// ---------------------------------------------------------------------------
// Fused kernel: MFMA forward-mode (value,grad,hess) + Einstein tail.
// Block = 1024 thr (16 waves), 16 samples. M=240 (m=c*16+sl), N=256, K=256
// per layer, K streamed in halves through one 65,280B LDS buffer.
// Wave w owns n-tile w (16 neurons) -> acc[15] = 60 AGPRs.
// Budget note: 4 waves/SIMD -> 128 unified regs/wave = 60 AGPR + ~64 VGPR.
// The epilogue therefore streams per accumulator row r (peak ~30 live) --
// materializing p[15][4] here caused an 85 MB scratch spill in R4.
// ---------------------------------------------------------------------------
template <bool TW>
__global__ __launch_bounds__(1024, 1) void mlp_fused(
    const float* __restrict__ coords,
    const float* __restrict__ W1, const float* __restrict__ b1,
    const float* __restrict__ W2, const float* __restrict__ b2,
    const float* __restrict__ W3, const float* __restrict__ b3,
    const float* __restrict__ Wo, const float* __restrict__ bo,
    const _Float16* __restrict__ Wt,   // packed f16 W2^T | W3^T (TW only)
    float* __restrict__ out, int B)
{
    __shared__ __align__(16) _Float16 st[MROWS * STRIDE];   // 65,280 B

    const int tid  = threadIdx.x;
    const int w    = tid >> 6;       // wave 0..15
    const int lane = tid & 63;
    const int col  = lane & 15;
    const int q    = lane >> 4;
    const int s0   = blockIdx.x * SPB;
    const int j    = w * 16 + col;   // neuron this lane accumulates

    floatx4 acc[NC];                 // 60 AGPRs
    _Float16 hold[NC * 4];           // 30 VGPRs, transient

    auto produce1 = [&](int half) {
        const int sl = tid & 15;
        const int cp = tid >> 4;                 // 0..63
        int ss = s0 + sl; if (ss >= B) ss = B - 1;
        const float x0 = coords[ss * 4 + 0];
        const float x1 = coords[ss * 4 + 1];
        const float x2 = coords[ss * 4 + 2];
        const float x3 = coords[ss * 4 + 3];
        const int jl0 = 2 * cp;
        const int jg  = half * KH + jl0;
        float2 wr0 = *(const float2*)&W1[0 * HDIM + jg];
        float2 wr1 = *(const float2*)&W1[1 * HDIM + jg];
        float2 wr2 = *(const float2*)&W1[2 * HDIM + jg];
        float2 wr3 = *(const float2*)&W1[3 * HDIM + jg];
        float2 bb  = *(const float2*)&b1[jg];
        float o2[2][NC];                         // constant-indexed -> regs
#pragma unroll
        for (int t = 0; t < 2; ++t) {
            float w0 = t ? wr0.y : wr0.x, w1 = t ? wr1.y : wr1.x;
            float w2v = t ? wr2.y : wr2.x, w3v = t ? wr3.y : wr3.x;
            float a = t ? bb.y : bb.x;
            a = fmaf(x0, w0, a); a = fmaf(x1, w1, a);
            a = fmaf(x2, w2v, a); a = fmaf(x3, w3v, a);
            float v = tanhf(a), tp = 1.f - v * v, m2 = -2.f * v * tp;
            float g[4] = {w0, w1, w2v, w3v};
            o2[t][0] = v;
            o2[t][1] = tp * w0; o2[t][2] = tp * w1;
            o2[t][3] = tp * w2v; o2[t][4] = tp * w3v;
            int idx = 5;
#pragma unroll
            for (int aa = 0; aa < 4; ++aa)
#pragma unroll
                for (int bb2 = aa; bb2 < 4; ++bb2) {
                    o2[t][idx] = m2 * g[aa] * g[bb2]; ++idx;
                }
        }
#pragma unroll
        for (int c = 0; c < NC; ++c) {
            half2h pk; pk[0] = (_Float16)o2[0][c]; pk[1] = (_Float16)o2[1][c];
            *(half2h*)&st[(c * 16 + sl) * STRIDE + jl0] = pk;
        }
    };

    auto init_acc = [&](const float* __restrict__ b) {
        float bj = b[j];
#pragma unroll
        for (int c = 0; c < NC; ++c)
#pragma unroll
            for (int r = 0; r < 4; ++r) acc[c][r] = 0.f;
#pragma unroll
        for (int r = 0; r < 4; ++r) acc[0][r] = bj;
    };

    auto gemm_half = [&](const float* __restrict__ W, int layer, int half) {
#pragma unroll
        for (int ks = 0; ks < 4; ++ks) {
            const int kg = half * KH + ks * 32 + q * 8;
            half8 bf;
            if constexpr (TW) {
                bf = *(const half8*)&Wt[(layer * HDIM + j) * HDIM + kg];
            } else {
#pragma unroll
                for (int i = 0; i < 8; ++i) bf[i] = (_Float16)W[(kg + i) * HDIM + j];
            }
#pragma unroll
            for (int mt = 0; mt < NC; ++mt) {
                half8 af = *(const half8*)&st[(mt * 16 + col) * STRIDE + ks * 32 + q * 8];
                acc[mt] = __builtin_amdgcn_mfma_f32_16x16x32_f16(af, bf, acc[mt], 0, 0, 0);
            }
        }
    };

    auto transform_hold = [&]() {
#pragma unroll
        for (int r = 0; r < 4; ++r) {
            float pre[NC];
#pragma unroll
            for (int c = 0; c < NC; ++c) pre[c] = acc[c][r];
            float v = tanhf(pre[0]), tp = 1.f - v * v, m2 = -2.f * v * tp;
            float g[4] = {pre[1], pre[2], pre[3], pre[4]};
            hold[0 * 4 + r] = (_Float16)v;
#pragma unroll
            for (int k = 0; k < 4; ++k) hold[(1 + k) * 4 + r] = (_Float16)(tp * g[k]);
            int idx = 5;
#pragma unroll
            for (int aa = 0; aa < 4; ++aa)
#pragma unroll
                for (int bb2 = aa; bb2 < 4; ++bb2) {
                    hold[idx * 4 + r] = (_Float16)fmaf(tp, pre[idx], m2 * g[aa] * g[bb2]);
                    ++idx;
                }
        }
    };

    auto store_hold = [&](int half) {
        const int jl = j - half * KH;            // in [0,128)
#pragma unroll
        for (int c = 0; c < NC; ++c)
#pragma unroll
            for (int r = 0; r < 4; ++r)
                st[(c * 16 + q * 4 + r) * STRIDE + jl] = hold[c * 4 + r];
    };

    // ================= pipeline =================
    produce1(0);
    __syncthreads();
    init_acc(b2);
    gemm_half(W2, 0, 0);
    __syncthreads();
    produce1(1);
    __syncthreads();
    gemm_half(W2, 0, 1);
    __syncthreads();                  // layer-1 state fully consumed
    transform_hold();                 // layer-2 state (f16, regs)
    if (w < 8) store_hold(0);         // waves owning j<128
    __syncthreads();
    init_acc(b3);
    gemm_half(W3, 1, 0);
    __syncthreads();
    if (w >= 8) store_hold(1);
    __syncthreads();
    gemm_half(W3, 1, 1);

    // ---- epilogue: layer-3 tanh chain + Wo dot, streamed per row r ----
    __syncthreads();                  // all st (A-frag) reads done; alias ok
    float* part = (float*)st;         // [0, 3840): part[w][c][sl]
    float* fin  = ((float*)st) + 4096;// [4096, 4352): fin[sl][c]
    const float wo = Wo[j];
#pragma unroll
    for (int r = 0; r < 4; ++r) {
        float pre[NC];
#pragma unroll
        for (int c = 0; c < NC; ++c) pre[c] = acc[c][r];
        float v = tanhf(pre[0]), tp = 1.f - v * v, m2 = -2.f * v * tp;
        float g0 = pre[1], g1 = pre[2], g2 = pre[3], g3 = pre[4];
        float on[NC];
        on[0] = wo * v;
        on[1] = wo * tp * g0; on[2] = wo * tp * g1;
        on[3] = wo * tp * g2; on[4] = wo * tp * g3;
        {
            float gg[4] = {g0, g1, g2, g3};
            int idx = 5;
#pragma unroll
            for (int aa = 0; aa < 4; ++aa)
#pragma unroll
                for (int bb2 = aa; bb2 < 4; ++bb2) {
                    on[idx] = wo * fmaf(tp, pre[idx], m2 * gg[aa] * gg[bb2]);
                    ++idx;
                }
        }
#pragma unroll
        for (int mask = 1; mask < 16; mask <<= 1)
#pragma unroll
            for (int c = 0; c < NC; ++c)
                on[c] += __shfl_xor(on[c], mask, 64);
        if (col == 0) {
#pragma unroll
            for (int c = 0; c < NC; ++c)
                part[w * MROWS + c * 16 + q * 4 + r] = on[c];
        }
    }
    __syncthreads();
    if (tid < MROWS) {
        float v = 0.f;
#pragma unroll
        for (int ww = 0; ww < 16; ++ww) v += part[ww * MROWS + tid];
        int c = tid >> 4, sl = tid & 15;
        if (c == 0) v += bo[0];
        fin[sl * 16 + c] = v;
    }
    __syncthreads();
    if (tid < SPB) {
        int s = s0 + tid;
        if (s < B) {
            float f = fin[tid * 16 + 0];
            float Gf[4], Hs[10];
#pragma unroll
            for (int k = 0; k < 4; ++k) Gf[k] = fin[tid * 16 + 1 + k];
#pragma unroll
            for (int qq = 0; qq < 10; ++qq) Hs[qq] = fin[tid * 16 + 5 + qq];
            float r  = coords[s * 4 + 1];
            float th = coords[s * 4 + 2];
            float res[16];
            einstein_tail(f, Gf, Hs, r, th, res);
#pragma unroll
            for (int e = 0; e < 16; ++e) out[s * 16 + e] = res[e];
        }
    }
}

extern "C" void kernel_launch(void* const* d_in, const int* in_sizes, int n_in,
                              void* d_out, int out_size, void* d_ws, size_t ws_size,
                              hipStream_t stream) {
    const float* coords = (const float*)d_in[0];
    const float* W1 = (const float*)d_in[1];
    const float* b1 = (const float*)d_in[2];
    const float* W2 = (const float*)d_in[3];
    const float* b2 = (const float*)d_in[4];
    const float* W3 = (const float*)d_in[5];
    const float* b3 = (const float*)d_in[6];
    const float* Wo = (const float*)d_in[7];
    const float* bo = (const float*)d_in[8];
    float* out = (float*)d_out;
    const int B = in_sizes[0] / 4;
    const int nblocks = (B + SPB - 1) / SPB;

    const size_t wt_bytes = (size_t)2 * HDIM * HDIM * sizeof(_Float16);
    if (ws_size >= wt_bytes) {
        _Float16* Wt = (_Float16*)d_ws;
        pack_wt<<<32, 256, 0, stream>>>(W2, W3, Wt);
        mlp_fused<true><<<nblocks, 1024, 0, stream>>>(
            coords, W1, b1, W2, b2, W3, b3, Wo, bo, Wt, out, B);
    } else {
        mlp_fused<false><<<nblocks, 1024, 0, stream>>>(
            coords, W1, b1, W2, b2, W3, b3, Wo, bo, nullptr, out, B);
    }
}

// Round 6
// 184.791 us; speedup vs baseline: 1.1140x; 1.1140x over previous
//
#include <hip/hip_runtime.h>
#include <math.h>

typedef _Float16 half8 __attribute__((ext_vector_type(8)));
typedef _Float16 half4h __attribute__((ext_vector_type(4)));
typedef float floatx4 __attribute__((ext_vector_type(4)));

#define HDIM 256
#define NC 15        // value + 4 grad + 10 hess (00,01,02,03,11,12,13,22,23,33)
#define SPB 16       // samples per block
#define KH 128       // K streamed in two halves
#define STRIDE 136   // f16 per LDS row: 128 + 8 pad
#define MROWS 240    // 15 comps * 16 samples
#define NWAVE 8

// ---------------------------------------------------------------------------
// Per-sample analytic Einstein tensor from (f, grad f, hess f). One lane.
// ---------------------------------------------------------------------------
__device__ __forceinline__ void einstein_tail(
    float f, const float* Gf, const float* Hs, float r, float th,
    float* __restrict__ outp)
{
    float Hf[4][4];
    {
        int qq = 0;
#pragma unroll
        for (int k = 0; k < 4; ++k)
#pragma unroll
            for (int l = k; l < 4; ++l) { Hf[k][l] = Hs[qq]; Hf[l][k] = Hs[qq]; ++qq; }
    }
    float sn = sinf(th), cs = cosf(th);
    float E  = expf(f);

    float gd[4] = {-1.f, E, r * r, r * r * sn * sn};
    float gi[4];
#pragma unroll
    for (int a = 0; a < 4; ++a) gi[a] = 1.f / gd[a];

    float dgv[4][4];
    float ddg[4][4][4];
#pragma unroll
    for (int a = 0; a < 4; ++a)
#pragma unroll
        for (int k = 0; k < 4; ++k) {
            dgv[a][k] = 0.f;
#pragma unroll
            for (int l = 0; l < 4; ++l) ddg[a][k][l] = 0.f;
        }
#pragma unroll
    for (int k = 0; k < 4; ++k) dgv[1][k] = E * Gf[k];
    dgv[2][1] = 2.f * r;
    dgv[3][1] = 2.f * r * sn * sn;
    dgv[3][2] = 2.f * r * r * sn * cs;
#pragma unroll
    for (int k = 0; k < 4; ++k)
#pragma unroll
        for (int l = 0; l < 4; ++l)
            ddg[1][k][l] = E * fmaf(Gf[k], Gf[l], Hf[k][l]);
    ddg[2][1][1] = 2.f;
    ddg[3][1][1] = 2.f * sn * sn;
    ddg[3][1][2] = 4.f * r * sn * cs;
    ddg[3][2][1] = 4.f * r * sn * cs;
    ddg[3][2][2] = 2.f * r * r * (cs * cs - sn * sn);

    auto SYMF = [&](int a, int i, int jx) -> float {
        float sy = 0.f;
        if (a == i)  sy += dgv[a][jx];
        if (a == jx) sy += dgv[a][i];
        if (i == jx) sy -= dgv[i][a];
        return sy;
    };
    auto DF = [&](int a, int i, int jx, int k) -> float {
        float ds = 0.f;
        if (a == i)  ds += ddg[a][jx][k];
        if (a == jx) ds += ddg[a][i][k];
        if (i == jx) ds -= ddg[i][a][k];
        return 0.5f * (gi[a] * ds - gi[a] * gi[a] * dgv[a][k] * SYMF(a, i, jx));
    };

    float Gm[4][4][4];
#pragma unroll
    for (int a = 0; a < 4; ++a)
#pragma unroll
        for (int i = 0; i < 4; ++i)
#pragma unroll
            for (int jx = 0; jx < 4; ++jx)
                Gm[a][i][jx] = 0.5f * gi[a] * SYMF(a, i, jx);

    float ric[4][4];
#pragma unroll
    for (int b = 0; b < 4; ++b)
#pragma unroll
        for (int d = 0; d < 4; ++d) {
            float sum = 0.f;
#pragma unroll
            for (int a = 0; a < 4; ++a) {
                sum += DF(a, d, b, a) - DF(a, a, b, d);
#pragma unroll
                for (int e = 0; e < 4; ++e)
                    sum += Gm[a][a][e] * Gm[e][d][b] - Gm[a][d][e] * Gm[e][a][b];
            }
            ric[b][d] = sum;
        }

    float Rs = 0.f;
#pragma unroll
    for (int b = 0; b < 4; ++b) Rs += gi[b] * ric[b][b];

#pragma unroll
    for (int a = 0; a < 4; ++a)
#pragma unroll
        for (int b = 0; b < 4; ++b) {
            float v = gi[a] * gi[b] * ric[a][b];
            if (a == b) v -= 0.5f * gi[a] * Rs;
            outp[a * 4 + b] = v;
        }
}

// ---------------------------------------------------------------------------
// Coalesced 64x64 LDS-tile transpose: Wt[m][j*256+k] = (f16)W_m[k*256+j].
// grid = 32 blocks (2 matrices x 16 tiles), block = 256.
// ---------------------------------------------------------------------------
__global__ __launch_bounds__(256) void pack_wt(
    const float* __restrict__ W2, const float* __restrict__ W3,
    _Float16* __restrict__ Wt)
{
    __shared__ float t[64][65];
    const int m    = blockIdx.x >> 4;
    const float* W = m ? W3 : W2;
    const int tile = blockIdx.x & 15;
    const int k0 = (tile >> 2) * 64, j0 = (tile & 3) * 64;
    const int tx = threadIdx.x & 63, ty = threadIdx.x >> 6;   // 64 x 4
#pragma unroll
    for (int i = 0; i < 16; ++i) {
        int k = ty + i * 4;
        t[k][tx] = W[(k0 + k) * HDIM + j0 + tx];              // coalesced read
    }
    __syncthreads();
#pragma unroll
    for (int i = 0; i < 16; ++i) {
        int jj = ty + i * 4;
        Wt[(size_t)m * HDIM * HDIM + (j0 + jj) * HDIM + k0 + tx] =
            (_Float16)t[tx][jj];                              // coalesced write
    }
}

// ---------------------------------------------------------------------------
// Fused kernel: MFMA forward-mode (value,grad,hess) + Einstein tail.
// Block = 512 thr (8 waves), 16 samples. M=240 (m=c*16+sl), N=256, K=256 per
// layer, K streamed in halves through one 65,280B LDS buffer.
// Wave w owns 2 n-tiles (32 neurons): acc[15][2] = 120 regs.
// REGISTER BUDGET (the R3-R5 lesson): 512 thr = 8 waves = 2 waves/SIMD ->
// 256 unified regs/wave. Peak live ~220. The previous 1024-thr shape (128
// regs/wave) forced ~100 MB/dispatch of scratch spill traffic.
// C/D layout (16x16x32): row=q*4+r = sample, col=lane&15 = neuron.
// ---------------------------------------------------------------------------
template <bool TW>
__global__ __launch_bounds__(512, 2) void mlp_fused(
    const float* __restrict__ coords,
    const float* __restrict__ W1, const float* __restrict__ b1,
    const float* __restrict__ W2, const float* __restrict__ b2,
    const float* __restrict__ W3, const float* __restrict__ b3,
    const float* __restrict__ Wo, const float* __restrict__ bo,
    const _Float16* __restrict__ Wt,   // packed f16 W2^T | W3^T (TW only)
    float* __restrict__ out, int B)
{
    __shared__ __align__(16) _Float16 st[MROWS * STRIDE];   // 65,280 B

    const int tid  = threadIdx.x;
    const int w    = tid >> 6;       // wave 0..7
    const int lane = tid & 63;
    const int col  = lane & 15;
    const int q    = lane >> 4;
    const int s0   = blockIdx.x * SPB;
    const int j0   = w * 32 + col;        // n-tile 0 neuron
    const int j1   = w * 32 + 16 + col;   // n-tile 1 neuron

    floatx4 acc[NC][2];              // 120 regs
    _Float16 hold[NC * 8];           // 60 regs, transient (c*8 + nt*4 + r)

    // ---- layer-1 producer: thread -> sample tid&15, col quad 4*(tid>>4) ----
    auto produce1 = [&](int half) {
        const int sl = tid & 15;
        const int cp = tid >> 4;                 // 0..31
        int ss = s0 + sl; if (ss >= B) ss = B - 1;
        const float x0 = coords[ss * 4 + 0];
        const float x1 = coords[ss * 4 + 1];
        const float x2 = coords[ss * 4 + 2];
        const float x3 = coords[ss * 4 + 3];
        const int jl0 = 4 * cp;
        const int jg  = half * KH + jl0;
        float4 wr0 = *(const float4*)&W1[0 * HDIM + jg];
        float4 wr1 = *(const float4*)&W1[1 * HDIM + jg];
        float4 wr2 = *(const float4*)&W1[2 * HDIM + jg];
        float4 wr3 = *(const float4*)&W1[3 * HDIM + jg];
        float4 bb  = *(const float4*)&b1[jg];
        float o2[4][NC];                         // constant-indexed -> regs
#pragma unroll
        for (int t = 0; t < 4; ++t) {
            float w0 = (&wr0.x)[t], w1 = (&wr1.x)[t];
            float w2v = (&wr2.x)[t], w3v = (&wr3.x)[t];
            float a = (&bb.x)[t];
            a = fmaf(x0, w0, a); a = fmaf(x1, w1, a);
            a = fmaf(x2, w2v, a); a = fmaf(x3, w3v, a);
            float v = tanhf(a), tp = 1.f - v * v, m2 = -2.f * v * tp;
            float g[4] = {w0, w1, w2v, w3v};
            o2[t][0] = v;
            o2[t][1] = tp * w0; o2[t][2] = tp * w1;
            o2[t][3] = tp * w2v; o2[t][4] = tp * w3v;
            int idx = 5;
#pragma unroll
            for (int aa = 0; aa < 4; ++aa)
#pragma unroll
                for (int bb2 = aa; bb2 < 4; ++bb2) {
                    o2[t][idx] = m2 * g[aa] * g[bb2]; ++idx;
                }
        }
#pragma unroll
        for (int c = 0; c < NC; ++c) {
            half4h pk;
            pk[0] = (_Float16)o2[0][c]; pk[1] = (_Float16)o2[1][c];
            pk[2] = (_Float16)o2[2][c]; pk[3] = (_Float16)o2[3][c];
            *(half4h*)&st[(c * 16 + sl) * STRIDE + jl0] = pk;
        }
    };

    auto init_acc = [&](const float* __restrict__ b) {
        float bj0 = b[j0], bj1 = b[j1];
#pragma unroll
        for (int c = 0; c < NC; ++c)
#pragma unroll
            for (int nt = 0; nt < 2; ++nt)
#pragma unroll
                for (int r = 0; r < 4; ++r) acc[c][nt][r] = 0.f;
#pragma unroll
        for (int r = 0; r < 4; ++r) { acc[0][0][r] = bj0; acc[0][1][r] = bj1; }
    };

    // GEMM over one K-half: A = st (f16 LDS), B = W rows [half*128, +128)
    auto gemm_half = [&](const float* __restrict__ W, int layer, int half) {
#pragma unroll
        for (int ks = 0; ks < 4; ++ks) {
            const int kg = half * KH + ks * 32 + q * 8;
            half8 bf0, bf1;
            if constexpr (TW) {
                bf0 = *(const half8*)&Wt[((size_t)layer * HDIM + j0) * HDIM + kg];
                bf1 = *(const half8*)&Wt[((size_t)layer * HDIM + j1) * HDIM + kg];
            } else {
#pragma unroll
                for (int i = 0; i < 8; ++i) {
                    bf0[i] = (_Float16)W[(kg + i) * HDIM + j0];
                    bf1[i] = (_Float16)W[(kg + i) * HDIM + j1];
                }
            }
#pragma unroll
            for (int mt = 0; mt < NC; ++mt) {
                half8 af = *(const half8*)&st[(mt * 16 + col) * STRIDE + ks * 32 + q * 8];
                acc[mt][0] = __builtin_amdgcn_mfma_f32_16x16x32_f16(af, bf0, acc[mt][0], 0, 0, 0);
                acc[mt][1] = __builtin_amdgcn_mfma_f32_16x16x32_f16(af, bf1, acc[mt][1], 0, 0, 0);
            }
        }
    };

    // tanh chain rule on acc -> hold (f16)
    auto transform_hold = [&]() {
#pragma unroll
        for (int nt = 0; nt < 2; ++nt)
#pragma unroll
            for (int r = 0; r < 4; ++r) {
                float pre[NC];
#pragma unroll
                for (int c = 0; c < NC; ++c) pre[c] = acc[c][nt][r];
                float v = tanhf(pre[0]), tp = 1.f - v * v, m2 = -2.f * v * tp;
                float g[4] = {pre[1], pre[2], pre[3], pre[4]};
                hold[0 * 8 + nt * 4 + r] = (_Float16)v;
#pragma unroll
                for (int k = 0; k < 4; ++k)
                    hold[(1 + k) * 8 + nt * 4 + r] = (_Float16)(tp * g[k]);
                int idx = 5;
#pragma unroll
                for (int aa = 0; aa < 4; ++aa)
#pragma unroll
                    for (int bb2 = aa; bb2 < 4; ++bb2) {
                        hold[idx * 8 + nt * 4 + r] =
                            (_Float16)fmaf(tp, pre[idx], m2 * g[aa] * g[bb2]);
                        ++idx;
                    }
            }
    };

    auto store_hold = [&](int half) {
#pragma unroll
        for (int nt = 0; nt < 2; ++nt) {
            const int jl = w * 32 + nt * 16 + col - half * KH;   // in [0,128)
#pragma unroll
            for (int c = 0; c < NC; ++c)
#pragma unroll
                for (int r = 0; r < 4; ++r)
                    st[(c * 16 + q * 4 + r) * STRIDE + jl] = hold[c * 8 + nt * 4 + r];
        }
    };

    // ================= pipeline =================
    produce1(0);
    __syncthreads();
    init_acc(b2);
    gemm_half(W2, 0, 0);
    __syncthreads();
    produce1(1);
    __syncthreads();
    gemm_half(W2, 0, 1);
    __syncthreads();                  // layer-1 state fully consumed
    transform_hold();                 // layer-2 state (f16, regs)
    if (w < 4) store_hold(0);         // waves owning j<128
    __syncthreads();
    init_acc(b3);
    gemm_half(W3, 1, 0);
    __syncthreads();
    if (w >= 4) store_hold(1);
    __syncthreads();
    gemm_half(W3, 1, 1);

    // ---- epilogue: layer-3 tanh chain + Wo dot, streamed per row r ----
    __syncthreads();                  // all st (A-frag) reads done; alias ok
    float* part = (float*)st;         // [0, 1920): part[w][c][sl]
    float* fin  = ((float*)st) + 4096;// [4096, 4352): fin[sl][c]
    const float wo0 = Wo[j0], wo1 = Wo[j1];
#pragma unroll
    for (int r = 0; r < 4; ++r) {
        float on[NC];
#pragma unroll
        for (int c = 0; c < NC; ++c) on[c] = 0.f;
#pragma unroll
        for (int nt = 0; nt < 2; ++nt) {
            const float wo = nt ? wo1 : wo0;
            float pre[NC];
#pragma unroll
            for (int c = 0; c < NC; ++c) pre[c] = acc[c][nt][r];
            float v = tanhf(pre[0]), tp = 1.f - v * v, m2 = -2.f * v * tp;
            float g0 = pre[1], g1 = pre[2], g2 = pre[3], g3 = pre[4];
            on[0] = fmaf(wo, v, on[0]);
            on[1] = fmaf(wo, tp * g0, on[1]);
            on[2] = fmaf(wo, tp * g1, on[2]);
            on[3] = fmaf(wo, tp * g2, on[3]);
            on[4] = fmaf(wo, tp * g3, on[4]);
            float gg[4] = {g0, g1, g2, g3};
            int idx = 5;
#pragma unroll
            for (int aa = 0; aa < 4; ++aa)
#pragma unroll
                for (int bb2 = aa; bb2 < 4; ++bb2) {
                    on[idx] = fmaf(wo, fmaf(tp, pre[idx], m2 * gg[aa] * gg[bb2]), on[idx]);
                    ++idx;
                }
        }
#pragma unroll
        for (int mask = 1; mask < 16; mask <<= 1)
#pragma unroll
            for (int c = 0; c < NC; ++c)
                on[c] += __shfl_xor(on[c], mask, 64);
        if (col == 0) {
#pragma unroll
            for (int c = 0; c < NC; ++c)
                part[w * MROWS + c * 16 + q * 4 + r] = on[c];
        }
    }
    __syncthreads();
    if (tid < MROWS) {
        float v = 0.f;
#pragma unroll
        for (int ww = 0; ww < NWAVE; ++ww) v += part[ww * MROWS + tid];
        int c = tid >> 4, sl = tid & 15;
        if (c == 0) v += bo[0];
        fin[sl * 16 + c] = v;
    }
    __syncthreads();
    if (tid < SPB) {
        int s = s0 + tid;
        if (s < B) {
            float f = fin[tid * 16 + 0];
            float Gf[4], Hs[10];
#pragma unroll
            for (int k = 0; k < 4; ++k) Gf[k] = fin[tid * 16 + 1 + k];
#pragma unroll
            for (int qq = 0; qq < 10; ++qq) Hs[qq] = fin[tid * 16 + 5 + qq];
            float r  = coords[s * 4 + 1];
            float th = coords[s * 4 + 2];
            float res[16];
            einstein_tail(f, Gf, Hs, r, th, res);
#pragma unroll
            for (int e = 0; e < 16; ++e) out[s * 16 + e] = res[e];
        }
    }
}

extern "C" void kernel_launch(void* const* d_in, const int* in_sizes, int n_in,
                              void* d_out, int out_size, void* d_ws, size_t ws_size,
                              hipStream_t stream) {
    const float* coords = (const float*)d_in[0];
    const float* W1 = (const float*)d_in[1];
    const float* b1 = (const float*)d_in[2];
    const float* W2 = (const float*)d_in[3];
    const float* b2 = (const float*)d_in[4];
    const float* W3 = (const float*)d_in[5];
    const float* b3 = (const float*)d_in[6];
    const float* Wo = (const float*)d_in[7];
    const float* bo = (const float*)d_in[8];
    float* out = (float*)d_out;
    const int B = in_sizes[0] / 4;
    const int nblocks = (B + SPB - 1) / SPB;

    const size_t wt_bytes = (size_t)2 * HDIM * HDIM * sizeof(_Float16);
    if (ws_size >= wt_bytes) {
        _Float16* Wt = (_Float16*)d_ws;
        pack_wt<<<32, 256, 0, stream>>>(W2, W3, Wt);
        mlp_fused<true><<<nblocks, 512, 0, stream>>>(
            coords, W1, b1, W2, b2, W3, b3, Wo, bo, Wt, out, B);
    } else {
        mlp_fused<false><<<nblocks, 512, 0, stream>>>(
            coords, W1, b1, W2, b2, W3, b3, Wo, bo, nullptr, out, B);
    }
}